// Round 1
// 3703.229 us; speedup vs baseline: 1.8273x; 1.8273x over previous
//
#include <hip/hip_runtime.h>
#include <hip/hip_bf16.h>

#define B_ 64
#define T_ 512
#define D_ 512
#define H_ 1024
#define G_ 4096
#define NJ 16              // j-columns per wg
#define WPD 64             // wgs per direction
#define WGS 128            // total wgs (1 per CU, half chip; latency-bound so idle CUs are free)
#define APE 520            // A-chunk row stride in u16 elems (1040 B = 1024 + 16 pad)
#define ABUF_B (64 * APE * 2)          // 66560 B per A chunk buffer
#define CT_OFF (2 * ABUF_B)            // 133120
#define CLP 66                         // C tile row stride (floats)
#define LDS_TOTAL (CT_OFF + 64 * CLP * 4)   // 150016 B

typedef unsigned short u16;
typedef __bf16 v8bf __attribute__((ext_vector_type(8)));
typedef unsigned short v8us __attribute__((ext_vector_type(8)));
typedef float v4f __attribute__((ext_vector_type(4)));

#define MFMA(a, b, c) __builtin_amdgcn_mfma_f32_16x16x32_bf16(a, b, c, 0, 0, 0)

__device__ __forceinline__ u16 f2bf(float f) {
    unsigned u = __builtin_bit_cast(unsigned, f);
    u += 0x7fffu + ((u >> 16) & 1u);   // RNE
    return (u16)(u >> 16);
}
__device__ __forceinline__ float sigm(float x) { return 1.0f / (1.0f + __expf(-x)); }
__device__ __forceinline__ float tanh_f(float x) { return 1.0f - 2.0f / (__expf(2.0f * x) + 1.0f); }

// async global->LDS, 16B per lane; lds dst must be wave-uniform base (lane*16 implicit)
__device__ __forceinline__ void gl_lds(const u16* g, u16* l) {
    __builtin_amdgcn_global_load_lds(
        (const __attribute__((address_space(1))) unsigned int*)g,
        (__attribute__((address_space(3))) unsigned int*)l, 16, 0, 0);
}
// device-coherent variant: cpol 17 = GLC|SCC -> "sc0 sc1" (bypass stale L1/L2, read at LLC)
__device__ __forceinline__ void gl_lds_c(const u16* g, u16* l) {
    __builtin_amdgcn_global_load_lds(
        (const __attribute__((address_space(1))) unsigned int*)g,
        (__attribute__((address_space(3))) unsigned int*)l, 16, 0, 17);
}

// ---------------- pre-pass: convert x to [T,B,D] bf16, zero h0 + gen flags ----------------
__global__ void prep_kernel(const float* __restrict__ xin, u16* __restrict__ xT,
                            u16* __restrict__ hb, int* __restrict__ gen) {
    int gid = blockIdx.x * 256 + threadIdx.x;           // over B*T*(D/4) = 4.19M
    if (gid < 65536) ((unsigned int*)hb)[gid] = 0u;     // parity-0 h buffers (256 KB)
    if (gid < 128) gen[gid] = 0;                        // generation flags (2 dirs x 64)
    int d0 = (gid & 127) * 4;
    int bt = gid >> 7;
    int b = bt >> 9, t = bt & 511;
    float4 v = *(const float4*)(xin + (size_t)bt * D_ + d0);
    ushort4 o;
    o.x = f2bf(v.x); o.y = f2bf(v.y); o.z = f2bf(v.z); o.w = f2bf(v.w);
    *(ushort4*)(xT + ((size_t)t * B_ + b) * D_ + d0) = o;
}

// ---------------- persistent scan kernel ----------------
// 128 wgs x 512 threads (8 waves), 1 wg/CU, 2 waves/SIMD.
// wave w: nt=w&3 (gate / 16-col n-tile), mh=w>>2 (32-row half). Full K=1536 per wave.
// W held in VGPRs (48 bf16x8 frags/lane). LDS: 2 A-chunk buffers + 1 C tile [64][66] f32.
// Coherence: h stores/loads are device-coherent (sc0 sc1) -> NO wbl2/inv fences in the loop.
// Barrier: per-wg generation flags (plain coherent stores, no RMW); wave0 ballot-polls.
extern "C" __global__ void __launch_bounds__(512, 2)
scan_kernel(const float* __restrict__ Wx_f, const float* __restrict__ Wh_f,
            const float* __restrict__ b_f,
            const float* __restrict__ Wx_b, const float* __restrict__ Wh_b,
            const float* __restrict__ b_b,
            const u16* __restrict__ xT, u16* __restrict__ hb,
            int* __restrict__ gen, float* __restrict__ out) {
    extern __shared__ char smem[];
    u16* Ab0 = (u16*)smem;
    u16* Ab1 = (u16*)(smem + ABUF_B);
    float* Cl = (float*)(smem + CT_OFF);   // [64][66] f32 z values

    const int tid = threadIdx.x;
    const int wg  = blockIdx.x;
    const int dir = wg & 1;
    const int wid = wg >> 1;               // 0..63
    const int j0  = wid * NJ;

    const float* Wx   = dir ? Wx_b : Wx_f;
    const float* Wh   = dir ? Wh_b : Wh_f;
    const float* bias = dir ? b_b  : b_f;

    const int w    = tid >> 6;
    const int lane = tid & 63;
    const int quad = lane >> 4;
    const int l15  = lane & 15;
    const int nt = w & 3;                  // gate index (i,f,o,g) == n-tile
    const int mh = w >> 2;                 // 32-row half of batch

    // ---- one-time: load W fragments into registers (B-operand: lane l15 = col) ----
    // col in [K,4G] weight matrix for this wave's tile: gate nt, column j0+l15
    const int zc = nt * H_ + j0 + l15;
    v8bf bfr[48];
    #pragma unroll
    for (int f = 0; f < 48; ++f) {
        const int kb = f * 32 + quad * 8;
        v8us tmp;
        #pragma unroll
        for (int e = 0; e < 8; ++e) {
            int k = kb + e;
            float wv = (k < D_) ? Wx[(size_t)k * G_ + zc]
                                : Wh[(size_t)(k - D_) * G_ + zc];
            tmp[e] = f2bf(wv);
        }
        bfr[f] = __builtin_bit_cast(v8bf, tmp);
    }

    // epilogue ownership: 512 threads <-> 64 b x 8 adjacent col-pairs (16 cols)
    const int ejj = (tid & 7) * 2, eb = tid >> 3;
    const float2 bI = *(const float2*)(bias + j0 + ejj);
    const float2 bF = *(const float2*)(bias + H_ + j0 + ejj);
    const float2 bO = *(const float2*)(bias + 2 * H_ + j0 + ejj);
    const float2 bG = *(const float2*)(bias + 3 * H_ + j0 + ejj);
    float c0s = 0.0f, c1s = 0.0f;

    // A-frag LDS offsets (u16 units); row stride APE=520 -> conflict-free b128
    const int ar0 = (mh * 32 + l15) * APE + quad * 8;
    const int ar1 = (mh * 32 + 16 + l15) * APE + quad * 8;
    const int srow = w * 8;                 // staging rows w*8..w*8+7
    const int loff = lane * 8;              // 16B per lane

    for (int s = 0; s < T_; ++s) {
        const int t  = dir ? (T_ - 1 - s) : s;
        const int pr = s & 1, pw = pr ^ 1;
        const u16* hbR = hb + (size_t)(pr * 2 + dir) * B_ * H_;

        // 1. stage c0 = x_t (K 0..511) into Ab0 — cached, no dependency on h
        {
            const u16* src = xT + (size_t)t * B_ * D_;
            #pragma unroll
            for (int r = 0; r < 8; ++r)
                gl_lds(src + (srow + r) * D_ + loff, Ab0 + (srow + r) * APE);
        }
        // 2. wave0 polls generation flags (one per lane), hidden under c0 flight
        if (w == 0) {
            const int* gp = gen + dir * 64 + lane;
            while (!__all(__hip_atomic_load(gp, __ATOMIC_RELAXED,
                                            __HIP_MEMORY_SCOPE_AGENT) >= s)) { }
        }
        __syncthreads();                                   // drains c0; releases all waves
        // 3. stage c1 = h cols 0..511 (K 512..1023) into Ab1 — coherent (sc0 sc1)
        #pragma unroll
        for (int r = 0; r < 8; ++r)
            gl_lds_c(hbR + (srow + r) * H_ + loff, Ab1 + (srow + r) * APE);
        // 4. compute c0 (frags 0..15), overlaps c1 flight
        v4f acc0 = {0.f, 0.f, 0.f, 0.f}, acc1 = {0.f, 0.f, 0.f, 0.f};
        #pragma unroll
        for (int f = 0; f < 16; ++f) {
            v8bf a0 = *(const v8bf*)(Ab0 + ar0 + f * 32);
            v8bf a1 = *(const v8bf*)(Ab0 + ar1 + f * 32);
            acc0 = MFMA(a0, bfr[f], acc0);
            acc1 = MFMA(a1, bfr[f], acc1);
        }
        __syncthreads();                                   // drains c1
        // 5. stage c2 = h cols 512..1023 (K 1024..1535) into Ab0 — coherent
        #pragma unroll
        for (int r = 0; r < 8; ++r)
            gl_lds_c(hbR + (srow + r) * H_ + 512 + loff, Ab0 + (srow + r) * APE);
        // 6. compute c1 (frags 16..31)
        #pragma unroll
        for (int f = 16; f < 32; ++f) {
            v8bf a0 = *(const v8bf*)(Ab1 + ar0 + (f - 16) * 32);
            v8bf a1 = *(const v8bf*)(Ab1 + ar1 + (f - 16) * 32);
            acc0 = MFMA(a0, bfr[f], acc0);
            acc1 = MFMA(a1, bfr[f], acc1);
        }
        __syncthreads();                                   // drains c2
        // 7. compute c2 (frags 32..47)
        #pragma unroll
        for (int f = 32; f < 48; ++f) {
            v8bf a0 = *(const v8bf*)(Ab0 + ar0 + (f - 32) * 32);
            v8bf a1 = *(const v8bf*)(Ab0 + ar1 + (f - 32) * 32);
            acc0 = MFMA(a0, bfr[f], acc0);
            acc1 = MFMA(a1, bfr[f], acc1);
        }
        // 8. write z tile (C layout: col = lane&15, row = quad*4+reg) — final, no kh combine
        #pragma unroll
        for (int r = 0; r < 4; ++r) {
            Cl[(mh * 32 + quad * 4 + r) * CLP + nt * 16 + l15]      = acc0[r];
            Cl[(mh * 32 + 16 + quad * 4 + r) * CLP + nt * 16 + l15] = acc1[r];
        }
        __syncthreads();
        // 9. epilogue: gates, c, h  (cols: i=0..15, f=16..31, o=32..47, g=48..63)
        {
            const float* C0 = Cl + eb * CLP;
            float2 zi = *(const float2*)(C0 + ejj);
            float2 zf = *(const float2*)(C0 + 16 + ejj);
            float2 zo = *(const float2*)(C0 + 32 + ejj);
            float2 zg = *(const float2*)(C0 + 48 + ejj);
            float iv0 = sigm(zi.x + bI.x), iv1 = sigm(zi.y + bI.y);
            float fv0 = sigm(zf.x + bF.x), fv1 = sigm(zf.y + bF.y);
            float ov0 = sigm(zo.x + bO.x), ov1 = sigm(zo.y + bO.y);
            float gv0 = tanh_f(zg.x + bG.x), gv1 = tanh_f(zg.y + bG.y);
            float cv0 = fv0 * c0s + iv0 * gv0; c0s = cv0;
            float cv1 = fv1 * c1s + iv1 * gv1; c1s = cv1;
            float hv0 = ov0 * tanh_f(cv0);
            float hv1 = ov1 * tanh_f(cv1);
            // h: packed 2x bf16, device-coherent write-through (sc0 sc1) -> at LLC when vmcnt drains
            unsigned hp = (unsigned)f2bf(hv0) | ((unsigned)f2bf(hv1) << 16);
            __hip_atomic_store(
                (unsigned*)(hb + (size_t)(pw * 2 + dir) * B_ * H_ + (size_t)eb * H_ + j0 + ejj),
                hp, __ATOMIC_RELAXED, __HIP_MEMORY_SCOPE_AGENT);
            // out: plain cached store (write-only; flushed at kernel end)
            float2 o2; o2.x = hv0; o2.y = hv1;
            *(float2*)(out + ((size_t)eb * T_ + t) * (2 * H_) + dir * H_ + j0 + ejj) = o2;
        }
        // 10. publish: __syncthreads drains vmcnt(0) for ALL waves' coherent h stores,
        //     then one plain coherent flag store (no RMW, no fence)
        __syncthreads();
        if (tid == 0) {
            asm volatile("s_waitcnt vmcnt(0)" ::: "memory");   // belt+suspenders, ~free
            __hip_atomic_store(gen + dir * 64 + wid, s + 1, __ATOMIC_RELAXED,
                               __HIP_MEMORY_SCOPE_AGENT);
        }
    }
}

extern "C" void kernel_launch(void* const* d_in, const int* in_sizes, int n_in,
                              void* d_out, int out_size, void* d_ws, size_t ws_size,
                              hipStream_t stream) {
    const float* xin  = (const float*)d_in[0];
    const float* Wx_f = (const float*)d_in[1];
    const float* Wh_f = (const float*)d_in[2];
    const float* b_f  = (const float*)d_in[3];
    const float* Wx_b = (const float*)d_in[4];
    const float* Wh_b = (const float*)d_in[5];
    const float* b_b  = (const float*)d_in[6];
    float* out = (float*)d_out;

    u16* xT = (u16*)d_ws;                                        // 32 MiB
    u16* hb = (u16*)((char*)d_ws + (size_t)T_ * B_ * D_ * 2);    // 512 KiB
    int* gen = (int*)((char*)d_ws + (size_t)T_ * B_ * D_ * 2 + 524288);

    hipLaunchKernelGGL(prep_kernel, dim3((B_ * T_ * (D_ / 4)) / 256), dim3(256), 0,
                       stream, xin, xT, hb, gen);

    hipFuncSetAttribute(reinterpret_cast<const void*>(scan_kernel),
                        hipFuncAttributeMaxDynamicSharedMemorySize, LDS_TOTAL);

    void* args[] = {(void*)&Wx_f, (void*)&Wh_f, (void*)&b_f,
                    (void*)&Wx_b, (void*)&Wh_b, (void*)&b_b,
                    (void*)&xT, (void*)&hb, (void*)&gen, (void*)&out};
    hipLaunchCooperativeKernel(reinterpret_cast<void*>(scan_kernel),
                               dim3(WGS), dim3(512), args, LDS_TOTAL, stream);
}